// Round 1
// 436.319 us; speedup vs baseline: 1.1413x; 1.1413x over previous
//
#include <hip/hip_runtime.h>
#include <hip/hip_bf16.h>
#include <math.h>

#define L_DIM 2048
#define B_DIM 64
#define D_DIM 512
#define A_DIM 64

#define SUB_L 16                      // l's resident in LDS per phase
#define CHUNK_L 64                    // l's per block
#define N_SUB (CHUNK_L / SUB_L)       // 4
#define N_CHUNK (L_DIM / CHUNK_L)     // 32
#define EPAD 520                      // bf16 row pitch (1040 B, 16B-aligned)

typedef __attribute__((ext_vector_type(8))) short bf16x8;
typedef __attribute__((ext_vector_type(4))) float f32x4;

__device__ __forceinline__ void split_bf16(float x, short& hi, short& lo) {
    __hip_bfloat16 h = __float2bfloat16(x);
    float hf = __bfloat162float(h);
    __hip_bfloat16 l = __float2bfloat16(x - hf);
    hi = *reinterpret_cast<short*>(&h);
    lo = *reinterpret_cast<short*>(&l);
}

__device__ __forceinline__ void split4(const float4& x, short4& h, short4& l) {
    split_bf16(x.x, h.x, l.x);
    split_bf16(x.y, h.y, l.y);
    split_bf16(x.z, h.z, l.z);
    split_bf16(x.w, h.w, l.w);
}

// reconstruct fp32 from split pair: hi+lo is exact in f32 (≤18 mantissa bits)
__device__ __forceinline__ float bf_hi_lo(short h, short l) {
    unsigned uh = ((unsigned)(unsigned short)h) << 16;
    unsigned ul = ((unsigned)(unsigned short)l) << 16;
    return __uint_as_float(uh) + __uint_as_float(ul);
}

// LDS-visibility barrier that does NOT drain vmcnt: keeps the enc prefetch
// in flight across the phase (plain __syncthreads() emits s_waitcnt vmcnt(0)).
__device__ __forceinline__ void lds_barrier() {
    asm volatile("s_waitcnt lgkmcnt(0)" ::: "memory");
    __builtin_amdgcn_s_barrier();
}

// ---------------------------------------------------------------------------
// Setup A: hb[b][a] = b_attn[a] + hidden[b] . W_hidden[:,a]
// ---------------------------------------------------------------------------
__global__ void hb_kernel(const float* __restrict__ hidden,
                          const float* __restrict__ Wh,
                          const float* __restrict__ battn,
                          float* __restrict__ hb) {
    const int b = blockIdx.x;
    const int a = threadIdx.x;
    const float* hrow = hidden + b * D_DIM;
    float acc = battn[a];
#pragma unroll 8
    for (int d = 0; d < D_DIM; ++d) acc += hrow[d] * Wh[d * A_DIM + a];
    hb[b * A_DIM + a] = acc;
}

// ---------------------------------------------------------------------------
// Setup B: transpose + split We (512x64 f32) -> wt_hi/wt_lo (64x512 bf16)
// ---------------------------------------------------------------------------
__global__ __launch_bounds__(256) void wt_kernel(const float* __restrict__ We,
                                                 short* __restrict__ wt_hi,
                                                 short* __restrict__ wt_lo) {
    const int idx = blockIdx.x * 256 + threadIdx.x;  // 0..32767
    const int a = idx & 63;
    const int d = idx >> 6;
    float x = We[d * A_DIM + a];
    short h, l;
    split_bf16(x, h, l);
    wt_hi[a * D_DIM + d] = h;
    wt_lo[a * D_DIM + d] = l;
}

// ---------------------------------------------------------------------------
// Fused kernel v3: grid (chunk=32, b=64), 256 threads (4 waves), 2 blocks/CU.
// Changes vs v2 (which spilled: VGPR_Count=68 with >=64 live prefetch regs):
//   - __launch_bounds__(256,2): up to 256 VGPRs, no scratch.
//   - B-fragments (wt_hi/wt_lo) hoisted to registers ONCE (128 VGPRs);
//     the K-loop is pure {ds_read_b128 x2, mfma x3} — no global loads.
//   - Single 32-VGPR prefetch buffer; merge re-reads E from LDS (hi+lo,
//     exact), so no second buffer / no cur<-nxt copy / no spill.
//   - Ehi/Elo double-buffered + raw s_barrier (lgkmcnt-only wait) so the
//     enc prefetch stays in flight across all barriers of the phase.
//   - 3 independent MFMA accumulator chains (depth 16 instead of 48).
// ---------------------------------------------------------------------------
__global__ __launch_bounds__(256, 2) void fused_kernel(
    const float* __restrict__ enc, const short* __restrict__ wt_hi,
    const short* __restrict__ wt_lo, const float* __restrict__ hb,
    const float* __restrict__ v, const int* __restrict__ lens,
    float* __restrict__ Om, float* __restrict__ mz) {
    const int c = blockIdx.x;      // chunk 0..31
    const int b = blockIdx.y;      // batch 0..63
    const int tid = threadIdx.x;
    const int wave = tid >> 6;     // 0..3  (a-tile)
    const int lane = tid & 63;
    const int quad = lane >> 4;    // 0..3
    const int l15 = lane & 15;
    const int po = tid & 127;      // float4 column 0..127 (d = po*4)
    const int par = tid >> 7;      // l-parity 0/1

    __shared__ short Ehi[2][SUB_L][EPAD];   // 2 x 16.6 KB
    __shared__ short Elo[2][SUB_L][EPAD];   // 2 x 16.6 KB
    __shared__ float sred[SUB_L][4];
    __shared__ float wl[SUB_L];
    __shared__ float msc[2];
    __shared__ float ored[D_DIM];           // 2 KB (parity merge)

    const int len_b = lens[b];
    const int a_col = wave * 16 + l15;
    const float hb0 = hb[b * A_DIM + a_col];
    const float v0 = v[a_col];

    // ---- hoist B fragments into registers, once per kernel ----
    const short* bh = wt_hi + (size_t)a_col * D_DIM + quad * 8;
    const short* bl = wt_lo + (size_t)a_col * D_DIM + quad * 8;
    bf16x8 Bh[16], Bl[16];
#pragma unroll
    for (int s = 0; s < 16; ++s) {
        Bh[s] = *(const bf16x8*)(bh + s * 32);
        Bl[s] = *(const bf16x8*)(bl + s * 32);
    }

    float4 Oacc = {0.f, 0.f, 0.f, 0.f};
    float mA = -INFINITY, ZA = 0.f;

    const float* encb = enc + (size_t)c * CHUNK_L * B_DIM * D_DIM +
                        (size_t)b * D_DIM + po * 4;
    const size_t ROWSTRIDE = (size_t)B_DIM * D_DIM;

    // single prefetch buffer: loaded for sub 0 here; re-issued each phase
    float4 buf[8];
#pragma unroll
    for (int j = 0; j < 8; ++j)
        buf[j] = *(const float4*)(encb + (size_t)(2 * j + par) * ROWSTRIDE);

#pragma unroll 2
    for (int sub = 0; sub < N_SUB; ++sub) {
        const int cb = sub & 1;

        // ---- stage buf -> LDS[cb] (split bf16) ----
#pragma unroll
        for (int j = 0; j < 8; ++j) {
            const int li = 2 * j + par;
            short4 h4, l4;
            split4(buf[j], h4, l4);
            *(short4*)&Ehi[cb][li][po * 4] = h4;
            *(short4*)&Elo[cb][li][po * 4] = l4;
        }
        lds_barrier();   // bar1: tile visible (no vmcnt drain)

        // ---- re-issue prefetch into the SAME regs (free after staging) ----
        if (sub + 1 < N_SUB) {
            const float* p = encb + (size_t)(sub + 1) * SUB_L * ROWSTRIDE;
#pragma unroll
            for (int j = 0; j < 8; ++j)
                buf[j] = *(const float4*)(p + (size_t)(2 * j + par) * ROWSTRIDE);
        }

        // ---- MFMA: P[l][a], split 3-product, 3 independent chains ----
        f32x4 a0 = {0.f, 0.f, 0.f, 0.f};
        f32x4 a1 = {0.f, 0.f, 0.f, 0.f};
        f32x4 a2 = {0.f, 0.f, 0.f, 0.f};
#pragma unroll
        for (int s = 0; s < 16; ++s) {
            const int k = s * 32;
            const bf16x8 Ah = *(const bf16x8*)&Ehi[cb][l15][k + quad * 8];
            const bf16x8 Al = *(const bf16x8*)&Elo[cb][l15][k + quad * 8];
            a0 = __builtin_amdgcn_mfma_f32_16x16x32_bf16(Ah, Bh[s], a0, 0, 0, 0);
            a1 = __builtin_amdgcn_mfma_f32_16x16x32_bf16(Ah, Bl[s], a1, 0, 0, 0);
            a2 = __builtin_amdgcn_mfma_f32_16x16x32_bf16(Al, Bh[s], a2, 0, 0, 0);
        }

        // ---- scores: C/D layout col=l15 (a), row=quad*4+r (l) ----
#pragma unroll
        for (int r = 0; r < 4; ++r) {
            float t = tanhf(a0[r] + a1[r] + a2[r] + hb0) * v0;
            t += __shfl_xor(t, 1);
            t += __shfl_xor(t, 2);
            t += __shfl_xor(t, 4);
            t += __shfl_xor(t, 8);
            if (l15 == 0) sred[quad * 4 + r][wave] = t;
        }
        lds_barrier();   // bar2

        if (tid < SUB_L) {
            const int lg = c * CHUNK_L + sub * SUB_L + tid;
            float s = sred[tid][0] + sred[tid][1] + sred[tid][2] + sred[tid][3];
            s = (lg < len_b) ? (s + 1.0f) : -INFINITY;
            float m = s;
            m = fmaxf(m, __shfl_xor(m, 1));
            m = fmaxf(m, __shfl_xor(m, 2));
            m = fmaxf(m, __shfl_xor(m, 4));
            m = fmaxf(m, __shfl_xor(m, 8));
            const float w = (m == -INFINITY) ? 0.f : expf(s - m);
            wl[tid] = w;
            float z = w;
            z += __shfl_xor(z, 1);
            z += __shfl_xor(z, 2);
            z += __shfl_xor(z, 4);
            z += __shfl_xor(z, 8);
            if (tid == 0) { msc[0] = m; msc[1] = z; }
        }
        lds_barrier();   // bar3

        // ---- online-softmax merge; E re-read from LDS (hi+lo, exact) ----
        const float m_sub = msc[0], Z_sub = msc[1];
        const float mN = fmaxf(mA, m_sub);
        const float cA = (mA == -INFINITY) ? 0.f : expf(mA - mN);
        const float cS = (m_sub == -INFINITY) ? 0.f : expf(m_sub - mN);
        Oacc.x *= cA; Oacc.y *= cA; Oacc.z *= cA; Oacc.w *= cA;
#pragma unroll
        for (int j = 0; j < 8; ++j) {
            const int li = 2 * j + par;
            const float w = cS * wl[li];
            const short4 h4 = *(const short4*)&Ehi[cb][li][po * 4];
            const short4 l4 = *(const short4*)&Elo[cb][li][po * 4];
            Oacc.x += w * bf_hi_lo(h4.x, l4.x);
            Oacc.y += w * bf_hi_lo(h4.y, l4.y);
            Oacc.z += w * bf_hi_lo(h4.z, l4.z);
            Oacc.w += w * bf_hi_lo(h4.w, l4.w);
        }
        ZA = cA * ZA + cS * Z_sub;
        mA = mN;
    }

    // ---- merge the two parity halves, write chunk partials ----
    if (par == 0) *(float4*)&ored[po * 4] = Oacc;
    __syncthreads();
    if (par == 1) {
        const float4 o0 = *(const float4*)&ored[po * 4];
        float4 r;
        r.x = o0.x + Oacc.x;
        r.y = o0.y + Oacc.y;
        r.z = o0.z + Oacc.z;
        r.w = o0.w + Oacc.w;
        *(float4*)(Om + ((size_t)b * N_CHUNK + c) * D_DIM + po * 4) = r;
    }
    if (tid == 0) {
        mz[((size_t)b * N_CHUNK + c) * 2 + 0] = mA;
        mz[((size_t)b * N_CHUNK + c) * 2 + 1] = ZA;
    }
}

// ---------------------------------------------------------------------------
// Combine: merge 32 chunk partials per b -> out[b][d]
// ---------------------------------------------------------------------------
__global__ __launch_bounds__(256) void combine_kernel(
    const float* __restrict__ Om, const float* __restrict__ mz,
    float* __restrict__ out) {
    const int b = blockIdx.x;
    const int tid = threadIdx.x;
    __shared__ float coef[N_CHUNK];
    __shared__ float sinv;

    if (tid < 32) {
        const float m = mz[((size_t)b * N_CHUNK + tid) * 2 + 0];
        const float Z = mz[((size_t)b * N_CHUNK + tid) * 2 + 1];
        float mm = m;
        mm = fmaxf(mm, __shfl_xor(mm, 1));
        mm = fmaxf(mm, __shfl_xor(mm, 2));
        mm = fmaxf(mm, __shfl_xor(mm, 4));
        mm = fmaxf(mm, __shfl_xor(mm, 8));
        mm = fmaxf(mm, __shfl_xor(mm, 16));
        const float cc = (m == -INFINITY) ? 0.f : expf(m - mm);
        coef[tid] = cc;
        float s = cc * Z;
        s += __shfl_xor(s, 1);
        s += __shfl_xor(s, 2);
        s += __shfl_xor(s, 4);
        s += __shfl_xor(s, 8);
        s += __shfl_xor(s, 16);
        if (tid == 0) sinv = 1.0f / s;
    }
    __syncthreads();

    const float* base = Om + (size_t)b * N_CHUNK * D_DIM + tid * 2;
    float ox = 0.f, oy = 0.f;
#pragma unroll 8
    for (int cc = 0; cc < N_CHUNK; ++cc) {
        const float2 x = *(const float2*)(base + cc * D_DIM);
        ox += coef[cc] * x.x;
        oy += coef[cc] * x.y;
    }
    const float s = sinv;
    *(float2*)(out + (size_t)b * D_DIM + tid * 2) = make_float2(ox * s, oy * s);
}

// ===========================================================================
extern "C" void kernel_launch(void* const* d_in, const int* in_sizes, int n_in,
                              void* d_out, int out_size, void* d_ws, size_t ws_size,
                              hipStream_t stream) {
    const float* enc    = (const float*)d_in[0];  // (L, B, 512)
    const int*   lens   = (const int*)d_in[1];    // (B,)
    const float* hidden = (const float*)d_in[2];  // (B, 512)
    const float* We     = (const float*)d_in[3];  // (512, 64)
    const float* battn  = (const float*)d_in[4];  // (64,)
    const float* Wh     = (const float*)d_in[5];  // (512, 64)
    const float* v      = (const float*)d_in[6];  // (64,)
    float* out = (float*)d_out;                   // (B, 512)

    // ws layout (bytes): hb @0 (16K) | wt_hi @16K (64K) | wt_lo @80K (64K)
    //                    | mz @144K (16K) | Om @160K (4 MB)
    char* w8 = (char*)d_ws;
    float* hb    = (float*)(w8 + 0);
    short* wt_hi = (short*)(w8 + 16 * 1024);
    short* wt_lo = (short*)(w8 + 80 * 1024);
    float* mz    = (float*)(w8 + 144 * 1024);
    float* Om    = (float*)(w8 + 160 * 1024);

    hb_kernel<<<B_DIM, A_DIM, 0, stream>>>(hidden, Wh, battn, hb);
    wt_kernel<<<(D_DIM * A_DIM) / 256, 256, 0, stream>>>(We, wt_hi, wt_lo);
    fused_kernel<<<dim3(N_CHUNK, B_DIM), 256, 0, stream>>>(
        enc, wt_hi, wt_lo, hb, v, lens, Om, mz);
    combine_kernel<<<B_DIM, 256, 0, stream>>>(Om, mz, out);
}

// Round 2
// 419.129 us; speedup vs baseline: 1.1881x; 1.0410x over previous
//
#include <hip/hip_runtime.h>
#include <hip/hip_bf16.h>
#include <math.h>

#define L_DIM 2048
#define B_DIM 64
#define D_DIM 512
#define A_DIM 64

#define SUB_L 16                      // l's resident in LDS per phase
#define CHUNK_L 64                    // l's per block
#define N_SUB (CHUNK_L / SUB_L)       // 4
#define N_CHUNK (L_DIM / CHUNK_L)     // 32
#define EPAD 520                      // bf16 row pitch (1040 B, 16B-aligned)

typedef __attribute__((ext_vector_type(8))) short bf16x8;
typedef __attribute__((ext_vector_type(4))) float f32x4;

// RNE split (setup only; one-time cost, best accuracy for the B matrix)
__device__ __forceinline__ void split_bf16(float x, short& hi, short& lo) {
    __hip_bfloat16 h = __float2bfloat16(x);
    float hf = __bfloat162float(h);
    __hip_bfloat16 l = __float2bfloat16(x - hf);
    hi = *reinterpret_cast<short*>(&h);
    lo = *reinterpret_cast<short*>(&l);
}

// Truncation split of a float PAIR -> packed hi16s and lo16s.
// hi = top 16 bits of x (1 v_perm per pair); residual x-hi_f is exact in f32;
// lo = top 16 bits of the residual. Pair error <= 2^-16 rel — far below the
// 2^-7 output tolerance. ~3 VALU/element vs ~10 for the RNE convert chain.
__device__ __forceinline__ void split_pair(float x, float y,
                                           unsigned& hi2, unsigned& lo2) {
    unsigned ux = __float_as_uint(x), uy = __float_as_uint(y);
    // D = [x.b2,x.b3,y.b2,y.b3] : S1=ux supplies bytes 0-3, S0=uy bytes 4-7
    hi2 = __builtin_amdgcn_perm(uy, ux, 0x07060302u);
    float rx = x - __uint_as_float(ux & 0xFFFF0000u);
    float ry = y - __uint_as_float(uy & 0xFFFF0000u);
    lo2 = __builtin_amdgcn_perm(__float_as_uint(ry), __float_as_uint(rx),
                                0x07060302u);
}

// reconstruct fp32 from split pair (exact to 2^-16 rel)
__device__ __forceinline__ float bf_hi_lo(short h, short l) {
    unsigned uh = ((unsigned)(unsigned short)h) << 16;
    unsigned ul = ((unsigned)(unsigned short)l) << 16;
    return __uint_as_float(uh) + __uint_as_float(ul);
}

// fast tanh via hardware exp2: ~6 insts, correct saturation at +-inf
__device__ __forceinline__ float fast_tanh(float x) {
    float e = __expf(2.0f * x);
    return 1.0f - 2.0f / (e + 1.0f);
}

// LDS-visibility barrier that does NOT drain vmcnt: keeps the enc prefetch
// in flight across the phase (plain __syncthreads() emits s_waitcnt vmcnt(0)).
__device__ __forceinline__ void lds_barrier() {
    asm volatile("s_waitcnt lgkmcnt(0)" ::: "memory");
    __builtin_amdgcn_s_barrier();
}

// ---------------------------------------------------------------------------
// Setup (one launch): blocks 0..63  -> hb[b][a] = b_attn[a] + hidden[b].Wh[:,a]
//                     blocks 64..95 -> transpose+split We -> wt_hi/wt_lo
// hb is d-sliced across 4 waves + LDS-reduced (4x the parallelism of v3).
// ---------------------------------------------------------------------------
__global__ __launch_bounds__(256) void setup_kernel(
    const float* __restrict__ hidden, const float* __restrict__ Wh,
    const float* __restrict__ battn, const float* __restrict__ We,
    float* __restrict__ hb, short* __restrict__ wt_hi,
    short* __restrict__ wt_lo) {
    __shared__ float part[4][A_DIM];
    if (blockIdx.x < 64) {
        const int b = blockIdx.x;
        const int a = threadIdx.x & 63;
        const int sl = threadIdx.x >> 6;          // d-slice 0..3
        const float* hrow = hidden + b * D_DIM + sl * 128;
        const float* wcol = Wh + (size_t)sl * 128 * A_DIM + a;
        float acc = 0.f;
#pragma unroll 8
        for (int d = 0; d < 128; ++d) acc += hrow[d] * wcol[(size_t)d * A_DIM];
        part[sl][a] = acc;
        __syncthreads();
        if (sl == 0)
            hb[b * A_DIM + a] =
                battn[a] + part[0][a] + part[1][a] + part[2][a] + part[3][a];
    } else {
        const int base = (blockIdx.x - 64) * 1024 + threadIdx.x * 4;
#pragma unroll
        for (int t = 0; t < 4; ++t) {
            const int i = base + t;
            const int a = i & 63;
            const int d = i >> 6;
            short h, l;
            split_bf16(We[i], h, l);
            wt_hi[a * D_DIM + d] = h;
            wt_lo[a * D_DIM + d] = l;
        }
    }
}

// ---------------------------------------------------------------------------
// Fused kernel v4: grid (chunk=32, b=64), 256 threads (4 waves), 2 blocks/CU.
// Changes vs v3:
//   - truncation split (v_perm based): staging VALU ~3x cheaper
//   - bar3 + tid<16 serial softmax removed: all waves redundantly reduce the
//     16 scores with 4-lane-group shfl_xor; merge weights via __shfl(w, li)
//   - fast __expf-based tanh/exp
// ---------------------------------------------------------------------------
__global__ __launch_bounds__(256, 2) void fused_kernel(
    const float* __restrict__ enc, const short* __restrict__ wt_hi,
    const short* __restrict__ wt_lo, const float* __restrict__ hb,
    const float* __restrict__ v, const int* __restrict__ lens,
    float* __restrict__ Om, float* __restrict__ mz) {
    const int c = blockIdx.x;      // chunk 0..31
    const int b = blockIdx.y;      // batch 0..63
    const int tid = threadIdx.x;
    const int wave = tid >> 6;     // 0..3  (a-tile)
    const int lane = tid & 63;
    const int quad = lane >> 4;    // 0..3
    const int l15 = lane & 15;
    const int po = tid & 127;      // float4 column 0..127 (d = po*4)
    const int par = tid >> 7;      // l-parity 0/1

    __shared__ short Ehi[2][SUB_L][EPAD];   // 2 x 16.6 KB
    __shared__ short Elo[2][SUB_L][EPAD];   // 2 x 16.6 KB
    __shared__ float sred[SUB_L][4];
    __shared__ float ored[D_DIM];           // 2 KB (parity merge)

    const int len_b = lens[b];
    const int a_col = wave * 16 + l15;
    const float hb0 = hb[b * A_DIM + a_col];
    const float v0 = v[a_col];

    // ---- hoist B fragments into registers, once per kernel ----
    const short* bh = wt_hi + (size_t)a_col * D_DIM + quad * 8;
    const short* bl = wt_lo + (size_t)a_col * D_DIM + quad * 8;
    bf16x8 Bh[16], Bl[16];
#pragma unroll
    for (int s = 0; s < 16; ++s) {
        Bh[s] = *(const bf16x8*)(bh + s * 32);
        Bl[s] = *(const bf16x8*)(bl + s * 32);
    }

    float4 Oacc = {0.f, 0.f, 0.f, 0.f};
    float mA = -INFINITY, ZA = 0.f;

    const float* encb = enc + (size_t)c * CHUNK_L * B_DIM * D_DIM +
                        (size_t)b * D_DIM + po * 4;
    const size_t ROWSTRIDE = (size_t)B_DIM * D_DIM;

    // single prefetch buffer: loaded for sub 0 here; re-issued each phase
    float4 buf[8];
#pragma unroll
    for (int j = 0; j < 8; ++j)
        buf[j] = *(const float4*)(encb + (size_t)(2 * j + par) * ROWSTRIDE);

#pragma unroll 2
    for (int sub = 0; sub < N_SUB; ++sub) {
        const int cb = sub & 1;

        // ---- stage buf -> LDS[cb] (truncation split, v_perm packed) ----
#pragma unroll
        for (int j = 0; j < 8; ++j) {
            const int li = 2 * j + par;
            uint2 h2, l2;
            split_pair(buf[j].x, buf[j].y, h2.x, l2.x);
            split_pair(buf[j].z, buf[j].w, h2.y, l2.y);
            *(uint2*)&Ehi[cb][li][po * 4] = h2;
            *(uint2*)&Elo[cb][li][po * 4] = l2;
        }
        lds_barrier();   // bar1: tile visible (no vmcnt drain)

        // ---- re-issue prefetch into the SAME regs (free after staging) ----
        if (sub + 1 < N_SUB) {
            const float* p = encb + (size_t)(sub + 1) * SUB_L * ROWSTRIDE;
#pragma unroll
            for (int j = 0; j < 8; ++j)
                buf[j] = *(const float4*)(p + (size_t)(2 * j + par) * ROWSTRIDE);
        }

        // ---- MFMA: P[l][a], split 3-product, 3 independent chains ----
        f32x4 a0 = {0.f, 0.f, 0.f, 0.f};
        f32x4 a1 = {0.f, 0.f, 0.f, 0.f};
        f32x4 a2 = {0.f, 0.f, 0.f, 0.f};
#pragma unroll
        for (int s = 0; s < 16; ++s) {
            const int k = s * 32;
            const bf16x8 Ah = *(const bf16x8*)&Ehi[cb][l15][k + quad * 8];
            const bf16x8 Al = *(const bf16x8*)&Elo[cb][l15][k + quad * 8];
            a0 = __builtin_amdgcn_mfma_f32_16x16x32_bf16(Ah, Bh[s], a0, 0, 0, 0);
            a1 = __builtin_amdgcn_mfma_f32_16x16x32_bf16(Ah, Bl[s], a1, 0, 0, 0);
            a2 = __builtin_amdgcn_mfma_f32_16x16x32_bf16(Al, Bh[s], a2, 0, 0, 0);
        }

        // ---- scores: C/D layout col=l15 (a), row=quad*4+r (l) ----
#pragma unroll
        for (int r = 0; r < 4; ++r) {
            float t = fast_tanh(a0[r] + a1[r] + a2[r] + hb0) * v0;
            t += __shfl_xor(t, 1);
            t += __shfl_xor(t, 2);
            t += __shfl_xor(t, 4);
            t += __shfl_xor(t, 8);
            if (l15 == 0) sred[quad * 4 + r][wave] = t;
        }
        lds_barrier();   // bar2: sred visible

        // ---- softmax over the 16 rows: every wave, all lanes (no bar3) ----
        // lane's row = l15; same-address LDS reads broadcast (free)
        float s = sred[l15][0] + sred[l15][1] + sred[l15][2] + sred[l15][3];
        const int lg = c * CHUNK_L + sub * SUB_L + l15;
        s = (lg < len_b) ? (s + 1.0f) : -INFINITY;
        float m = s;
        m = fmaxf(m, __shfl_xor(m, 1));
        m = fmaxf(m, __shfl_xor(m, 2));
        m = fmaxf(m, __shfl_xor(m, 4));
        m = fmaxf(m, __shfl_xor(m, 8));
        const float w = (m == -INFINITY) ? 0.f : __expf(s - m);
        float z = w;
        z += __shfl_xor(z, 1);
        z += __shfl_xor(z, 2);
        z += __shfl_xor(z, 4);
        z += __shfl_xor(z, 8);
        // m, z uniform across all lanes/waves (identical redundant compute)

        // ---- online-softmax merge; E re-read from LDS (hi+lo) ----
        const float mN = fmaxf(mA, m);
        const float cA = (mA == -INFINITY) ? 0.f : __expf(mA - mN);
        const float cS = (m == -INFINITY) ? 0.f : __expf(m - mN);
        Oacc.x *= cA; Oacc.y *= cA; Oacc.z *= cA; Oacc.w *= cA;
#pragma unroll
        for (int j = 0; j < 8; ++j) {
            const int li = 2 * j + par;
            const float wgt = cS * __shfl(w, li);   // w held by lane li
            const short4 h4 = *(const short4*)&Ehi[cb][li][po * 4];
            const short4 l4 = *(const short4*)&Elo[cb][li][po * 4];
            Oacc.x += wgt * bf_hi_lo(h4.x, l4.x);
            Oacc.y += wgt * bf_hi_lo(h4.y, l4.y);
            Oacc.z += wgt * bf_hi_lo(h4.z, l4.z);
            Oacc.w += wgt * bf_hi_lo(h4.w, l4.w);
        }
        ZA = cA * ZA + cS * z;
        mA = mN;
    }

    // ---- merge the two parity halves, write chunk partials ----
    if (par == 0) *(float4*)&ored[po * 4] = Oacc;
    __syncthreads();
    if (par == 1) {
        const float4 o0 = *(const float4*)&ored[po * 4];
        float4 r;
        r.x = o0.x + Oacc.x;
        r.y = o0.y + Oacc.y;
        r.z = o0.z + Oacc.z;
        r.w = o0.w + Oacc.w;
        *(float4*)(Om + ((size_t)b * N_CHUNK + c) * D_DIM + po * 4) = r;
    }
    if (tid == 0) {
        mz[((size_t)b * N_CHUNK + c) * 2 + 0] = mA;
        mz[((size_t)b * N_CHUNK + c) * 2 + 1] = ZA;
    }
}

// ---------------------------------------------------------------------------
// Combine: merge 32 chunk partials per b -> out[b][d]
// ---------------------------------------------------------------------------
__global__ __launch_bounds__(256) void combine_kernel(
    const float* __restrict__ Om, const float* __restrict__ mz,
    float* __restrict__ out) {
    const int b = blockIdx.x;
    const int tid = threadIdx.x;
    __shared__ float coef[N_CHUNK];
    __shared__ float sinv;

    if (tid < 32) {
        const float m = mz[((size_t)b * N_CHUNK + tid) * 2 + 0];
        const float Z = mz[((size_t)b * N_CHUNK + tid) * 2 + 1];
        float mm = m;
        mm = fmaxf(mm, __shfl_xor(mm, 1));
        mm = fmaxf(mm, __shfl_xor(mm, 2));
        mm = fmaxf(mm, __shfl_xor(mm, 4));
        mm = fmaxf(mm, __shfl_xor(mm, 8));
        mm = fmaxf(mm, __shfl_xor(mm, 16));
        const float cc = (m == -INFINITY) ? 0.f : __expf(m - mm);
        coef[tid] = cc;
        float s = cc * Z;
        s += __shfl_xor(s, 1);
        s += __shfl_xor(s, 2);
        s += __shfl_xor(s, 4);
        s += __shfl_xor(s, 8);
        s += __shfl_xor(s, 16);
        if (tid == 0) sinv = 1.0f / s;
    }
    __syncthreads();

    const float* base = Om + (size_t)b * N_CHUNK * D_DIM + tid * 2;
    float ox = 0.f, oy = 0.f;
#pragma unroll 8
    for (int cc = 0; cc < N_CHUNK; ++cc) {
        const float2 x = *(const float2*)(base + cc * D_DIM);
        ox += coef[cc] * x.x;
        oy += coef[cc] * x.y;
    }
    const float s = sinv;
    *(float2*)(out + (size_t)b * D_DIM + tid * 2) = make_float2(ox * s, oy * s);
}

// ===========================================================================
extern "C" void kernel_launch(void* const* d_in, const int* in_sizes, int n_in,
                              void* d_out, int out_size, void* d_ws, size_t ws_size,
                              hipStream_t stream) {
    const float* enc    = (const float*)d_in[0];  // (L, B, 512)
    const int*   lens   = (const int*)d_in[1];    // (B,)
    const float* hidden = (const float*)d_in[2];  // (B, 512)
    const float* We     = (const float*)d_in[3];  // (512, 64)
    const float* battn  = (const float*)d_in[4];  // (64,)
    const float* Wh     = (const float*)d_in[5];  // (512, 64)
    const float* v      = (const float*)d_in[6];  // (64,)
    float* out = (float*)d_out;                   // (B, 512)

    // ws layout (bytes): hb @0 (16K) | wt_hi @16K (64K) | wt_lo @80K (64K)
    //                    | mz @144K (16K) | Om @160K (4 MB)
    char* w8 = (char*)d_ws;
    float* hb    = (float*)(w8 + 0);
    short* wt_hi = (short*)(w8 + 16 * 1024);
    short* wt_lo = (short*)(w8 + 80 * 1024);
    float* mz    = (float*)(w8 + 144 * 1024);
    float* Om    = (float*)(w8 + 160 * 1024);

    setup_kernel<<<96, 256, 0, stream>>>(hidden, Wh, battn, We, hb, wt_hi, wt_lo);
    fused_kernel<<<dim3(N_CHUNK, B_DIM), 256, 0, stream>>>(
        enc, wt_hi, wt_lo, hb, v, lens, Om, mz);
    combine_kernel<<<B_DIM, 256, 0, stream>>>(Om, mz, out);
}